// Round 9
// baseline (428.761 us; speedup 1.0000x reference)
//
#include <hip/hip_runtime.h>
#include <hip/hip_cooperative_groups.h>

namespace cg = cooperative_groups;

struct Params {
  const float *X, *E, *nbr;
  const float *embW, *embB, *boutW, *boutB;
  const float *qpW, *qpB, *kpW, *kpB, *qoW, *qoB, *koW, *koB;
  const float *bpW, *bpB, *bowW, *bowB;
  const float *qlnG, *qlnB, *klnG, *klnB;
  float *out;
  float *pk2;        // [2][256][512] keys, layer-parity double-buffered
  float *bz, *bg;    // [2][512]  bias-pipe intermediate b, zero/gen class
  float *rowz, *rowg;// [2][128]  bias rows, zero/gen class
  float *partial;    // [4][2][256] per-block squared-norm partials (h = i>>6)
  float *rareBias;   // [65536][128] rare-pair rows (unused in this data)
};

__device__ __forceinline__ float mishf(float x) {
  float sp = (x > 20.f) ? x : log1pf(expf(x));
  return x * tanhf(sp);
}

// Full per-row bias pipe (rare pairs only; own-block, barriers inside)
__device__ void bias_row_pipe(float* row, float* drow,
                              const float* __restrict__ Wp, const float* __restrict__ Bp,
                              const float* __restrict__ Wo, const float* __restrict__ Bo,
                              float* smW, float* smB, int t) {
  const int lane = t & 63, wave = t >> 6;
  if (t < 128) smB[t] = row[t];
  __syncthreads();
  {
    const int o = t & 511, kh = t >> 9;
    const float* Wc = Wp + (kh * 64) * 512 + o;
    const float* rc = smB + kh * 64;
    float a = (kh == 0) ? Bp[o] : 0.f;
    #pragma unroll 8
    for (int c = 0; c < 64; ++c) a = fmaf(rc[c], Wc[c * 512], a);
    smW[t] = a;
  }
  __syncthreads();
  if (t < 512) smB[128 + t] = smW[t] + smW[512 + t];
  __syncthreads();
  if (wave < 4) {
    float e1 = smB[128 + wave * 128 + lane], e2 = smB[128 + wave * 128 + 64 + lane];
    float s = e1 * e1 + e2 * e2;
    #pragma unroll
    for (int sh = 32; sh; sh >>= 1) s += __shfl_xor(s, sh);
    if (lane == 0) drow[wave] = sqrtf(s);
  }
  {
    const int c = t & 127, ch = t >> 7;
    const float* Woc = Wo + (ch * 64) * 128 + c;
    const float* bc = smB + 128 + ch * 64;
    float a = 0.f;
    #pragma unroll 8
    for (int o2 = 0; o2 < 64; ++o2) a = fmaf(bc[o2], Woc[o2 * 128], a);
    smW[t] = a;
  }
  __syncthreads();
  if (t < 128) {
    float a = Bo[t];
    #pragma unroll
    for (int j = 0; j < 8; ++j) a += smW[t + 128 * j];
    row[t] = mishf(a);
  }
  __syncthreads();
}

// Distributed GEMM1 slice: block b computes cols {2b,2b+1} of b_l for both
// classes + the squared-norm partial. wave 0 only, no barriers.
__device__ void b_slice(const Params& P, int b, int lane, int wave, int l, bool analytic) {
  if (wave != 0) return;
  const int c0 = 2 * b, par = l & 1;
  const float* Wp = P.bpW + (size_t)l * 65536;
  float azx = 0.f, azy = 0.f, agx = 0.f, agy = 0.f;
  #pragma unroll
  for (int jj = 0; jj < 2; ++jj) {
    int j = lane + 64 * jj;
    float rz, rg;
    if (analytic) { float cc = (float)j * (1.f / 127.f); rz = expf(-127.f * cc * cc); rg = 0.f; }
    else { rz = P.rowz[par * 128 + j]; rg = P.rowg[par * 128 + j]; }
    float2 w = *(const float2*)(Wp + j * 512 + c0);
    azx = fmaf(rz, w.x, azx); azy = fmaf(rz, w.y, azy);
    agx = fmaf(rg, w.x, agx); agy = fmaf(rg, w.y, agy);
  }
  #pragma unroll
  for (int s = 32; s; s >>= 1) {
    azx += __shfl_xor(azx, s); azy += __shfl_xor(azy, s);
    agx += __shfl_xor(agx, s); agy += __shfl_xor(agy, s);
  }
  if (lane == 0) {
    float b0 = P.bpB[l * 512 + c0], b1 = P.bpB[l * 512 + c0 + 1];
    float zx = azx + b0, zy = azy + b1, gx = agx + b0, gy = agy + b1;
    P.bz[par * 512 + c0] = zx; P.bz[par * 512 + c0 + 1] = zy;
    P.bg[par * 512 + c0] = gx; P.bg[par * 512 + c0 + 1] = gy;
    P.partial[(l * 2 + 0) * 256 + b] = zx * zx + zy * zy;
    P.partial[(l * 2 + 1) * 256 + b] = gx * gx + gy * gy;
  }
}

// Distributed GEMM2 slice: block b<128 computes element b of row_{l+1} for
// both classes. wave 0 only, no barriers.
__device__ void row_slice(const Params& P, int b, int lane, int wave, int l) {
  if (b >= 128 || wave != 0) return;
  const int i = b, par = l & 1;
  const float* Wo = P.bowW + (size_t)l * 65536;
  float az = 0.f, ag = 0.f;
  #pragma unroll
  for (int jj = 0; jj < 8; ++jj) {
    int o = lane + 64 * jj;
    float w = Wo[o * 128 + i];
    az = fmaf(P.bz[par * 512 + o], w, az);
    ag = fmaf(P.bg[par * 512 + o], w, ag);
  }
  #pragma unroll
  for (int s = 32; s; s >>= 1) { az += __shfl_xor(az, s); ag += __shfl_xor(ag, s); }
  if (lane == 0) {
    float bo = P.bowB[l * 128 + i];
    P.rowz[((l + 1) & 1) * 128 + i] = mishf(az + bo);
    P.rowg[((l + 1) & 1) * 128 + i] = mishf(ag + bo);
  }
}

// 256 blocks x 1024 threads; per-n state persistent in LDS; 7 grid syncs
__global__ void __launch_bounds__(1024, 4) crakn(Params P) {
  cg::grid_group grid = cg::this_grid();
  const int b = blockIdx.x, t = threadIdx.x;
  const int lane = t & 63, wave = t >> 6;
  const int n = b;

  // persistent
  __shared__ float smP[512], smKr[512];
  __shared__ float smQ[64], smKq[64];
  __shared__ float smNbr[256];
  __shared__ int   smMap[256];
  __shared__ float smPD[2048];
  __shared__ float smPred[1];
  __shared__ int   smI[257];
  __shared__ float smD[256];
  // scratch
  __shared__ float smW[1024];
  __shared__ float smB[640];
  __shared__ float smH[64];
  __shared__ float smDf[8];

  // ================= Region P =================
  {
    if (t < 256) smB[t] = P.X[n * 256 + t];
    if (t < 256) smNbr[t] = P.nbr[t];
    if (t == 0) smI[256] = 0;
    __syncthreads();
    {
      const int d = t & 63, ch = t >> 6;
      const float* W = P.embW + (ch * 16) * 64 + d;
      const float* xr = smB + ch * 16;
      float acc = 0.f;
      #pragma unroll
      for (int f = 0; f < 16; ++f) acc = fmaf(xr[f], W[f * 64], acc);
      smW[t] = acc;
    }
    float pp = (t < 256) ? smB[t] * P.boutW[t] : 0.f;
    #pragma unroll
    for (int s = 32; s; s >>= 1) pp += __shfl_xor(pp, s);
    if (t < 256 && lane == 0) smH[wave] = pp;
    __syncthreads();
    if (t < 64) {
      float nd = P.embB[t];
      #pragma unroll
      for (int j = 0; j < 16; ++j) nd += smW[t + 64 * j];
      smQ[t] = nd; smKq[t] = nd;
    }
    if (t == 0) smPred[0] = smH[0] + smH[1] + smH[2] + smH[3] + P.boutB[0];
    __syncthreads();
    if (t < 25) ((float4*)(smB + 384))[t] = ((const float4*)(P.E + n * 100))[t];
    __syncthreads();
    if (t < 256) {                      // distances, thread = m
      const int m = t;
      const float4* em = (const float4*)(P.E + m * 100);
      const float4* en = (const float4*)(smB + 384);
      float sq = 0.f;
      #pragma unroll 5
      for (int jj = 0; jj < 25; ++jj) {
        float4 a = en[jj], c = em[jj];
        float dx = a.x - c.x, dy = a.y - c.y, dz = a.z - c.z, dw = a.w - c.w;
        sq += dx * dx + dy * dy + dz * dz + dw * dw;
      }
      float dd = (sq > 0.f) ? sqrtf(sq) : 0.f;
      // exp(-127*(d-c)^2), c in [0,1]: fp32-underflows to exactly 0 for d>=1.905.
      // d==0 rows identical -> shared zero-class; underflow -> shared gen-class.
      int mv;
      if (dd == 0.f) mv = -2;
      else if (dd < 1.905f) {
        int i = atomicAdd(&smI[256], 1);
        smI[i] = m; smD[i] = dd;
        mv = i;
      } else mv = -1;
      smMap[m] = mv;
    }
    __syncthreads();
    {                                   // rare per-pair RBF rows (none in practice)
      int cnt = smI[256]; if (cnt > 256) cnt = 256;
      for (int i = 0; i < cnt; ++i) if (t < 128) {
        float dd = smD[i] - (float)t * (1.f / 127.f);
        P.rareBias[(size_t)(n * 256 + i) * 128 + t] = expf(-127.f * dd * dd);
      }
    }
    __syncthreads();
    {                                   // proj(0)
      const int g = t >> 9, u = t & 511;
      const float* Wp = (g ? P.kpW : P.qpW);
      const float* Bp = (g ? P.kpB : P.qpB);
      const float* xs = g ? smKq : smQ;
      float a = Bp[u];
      #pragma unroll 8
      for (int d = 0; d < 64; ++d) a = fmaf(xs[d], Wp[d * 512 + u], a);
      if (g) { smKr[u] = a; P.pk2[n * 512 + u] = a; }
      else   { smP[u] = a; }
    }
    b_slice(P, b, lane, wave, 0, true);
    __syncthreads();
    {                                   // rare pipes layer 0 (parity 0)
      int cnt = smI[256]; if (cnt > 256) cnt = 256;
      for (int i = 0; i < cnt; ++i)
        bias_row_pipe(P.rareBias + (size_t)(n * 256 + i) * 128, smPD + i * 8,
                      P.bpW, P.bpB, P.bowW, P.bowB, smW, smB, t);
    }
  }

  for (int l = 0; l < 4; ++l) {
    grid.sync();
    const int par = l & 1;
    // ====== R_l: diff reduce + attention + row slices ======
    if (t < 256) {                      // wave w sums head w's partials
      float pz = P.partial[(l * 2 + 0) * 256 + t];
      float pg = P.partial[(l * 2 + 1) * 256 + t];
      #pragma unroll
      for (int s = 32; s; s >>= 1) { pz += __shfl_xor(pz, s); pg += __shfl_xor(pg, s); }
      if (lane == 0) { smDf[wave] = sqrtf(pz); smDf[4 + wave] = sqrtf(pg); }
    }
    __syncthreads();
    {
      const int h = t >> 8, m = t & 255;
      const int cls = smMap[m];
      const float bd = (cls == -2) ? smDf[h] : (cls == -1) ? smDf[4 + h]
                     : smPD[cls * 8 + par * 4 + h];
      const float val = (m == n) ? smPred[0] : smNbr[m];
      const float4* kp = (const float4*)(P.pk2 + (size_t)par * 131072 + m * 512 + h * 128);
      const float4* qp = (const float4*)(smP + h * 128);
      float dot = 0.f;
      #pragma unroll 8
      for (int j = 0; j < 32; ++j) {
        float4 kv = kp[j], qv = qp[j];
        dot = fmaf(qv.x, kv.x, dot); dot = fmaf(qv.y, kv.y, dot);
        dot = fmaf(qv.z, kv.z, dot); dot = fmaf(qv.w, kv.w, dot);
      }
      float lg = dot * 0.08838834764831845f + bd;   // 1/sqrt(128)
      float wm = lg;
      #pragma unroll
      for (int s = 32; s; s >>= 1) wm = fmaxf(wm, __shfl_xor(wm, s));
      if (lane == 0) smH[wave] = wm;
      __syncthreads();
      float mx = fmaxf(fmaxf(smH[h * 4], smH[h * 4 + 1]),
                       fmaxf(smH[h * 4 + 2], smH[h * 4 + 3]));
      float e = expf(lg - mx);
      float s1 = e, s2 = e * val;
      #pragma unroll
      for (int s = 32; s; s >>= 1) { s1 += __shfl_xor(s1, s); s2 += __shfl_xor(s2, s); }
      if (lane == 0) { smH[16 + wave] = s1; smH[32 + wave] = s2; }
      __syncthreads();
      if (t == 0) {
        float p = 0.f;
        #pragma unroll
        for (int hh = 0; hh < 4; ++hh) {
          float den = smH[16 + hh * 4] + smH[17 + hh * 4] + smH[18 + hh * 4] + smH[19 + hh * 4];
          float ws  = smH[32 + hh * 4] + smH[33 + hh * 4] + smH[34 + hh * 4] + smH[35 + hh * 4];
          p += 0.25f * (ws / den);
        }
        smPred[0] = p;
        if (l == 3) P.out[n] = p;
      }
      __syncthreads();
    }
    if (l == 3) break;
    row_slice(P, b, lane, wave, l);     // row_{l+1} slices (blocks <128, wave 0)
    grid.sync();
    // ====== D_l: Bupd(l) + proj(l+1) + b_{l+1} slices + rare pipes ======
    {
      const int g = t >> 9, u = t & 511;
      const float* prow = g ? smKr : smP;
      const float* W = (g ? P.koW : P.qoW) + (size_t)l * 32768;
      {
        const int d = u & 63, ch = u >> 6;
        float acc = 0.f;
        #pragma unroll 8
        for (int rr = 0; rr < 64; ++rr) {
          int r = ch * 64 + rr;
          acc = fmaf(prow[((r & 3) << 7) | (r >> 2)], W[r * 64 + d], acc);
        }
        smW[t] = acc;
      }
      __syncthreads();
      if (u < 64) {
        float* x = g ? smKq : smQ;
        const float* B = (g ? P.koB : P.qoB) + l * 64;
        float acc = B[u];
        #pragma unroll
        for (int j = 0; j < 8; ++j) acc += smW[g * 512 + u + 64 * j];
        float xv = x[u] + mishf(acc);
        float mean = xv;
        #pragma unroll
        for (int s = 32; s; s >>= 1) mean += __shfl_xor(mean, s);
        mean *= (1.f / 64.f);
        float dv = xv - mean, var = dv * dv;
        #pragma unroll
        for (int s = 32; s; s >>= 1) var += __shfl_xor(var, s);
        var *= (1.f / 64.f);
        const float* G  = (g ? P.klnG : P.qlnG) + l * 64;
        const float* Bb = (g ? P.klnB : P.qlnB) + l * 64;
        x[u] = dv * rsqrtf(var + 1e-5f) * G[u] + Bb[u];
      }
      __syncthreads();
    }
    {                                   // proj(l+1)
      const int g = t >> 9, u = t & 511;
      const float* Wp = (g ? P.kpW : P.qpW) + (size_t)(l + 1) * 32768;
      const float* Bp = (g ? P.kpB : P.qpB) + (l + 1) * 512;
      const float* xs = g ? smKq : smQ;
      float a = Bp[u];
      #pragma unroll 8
      for (int d = 0; d < 64; ++d) a = fmaf(xs[d], Wp[d * 512 + u], a);
      if (g) { smKr[u] = a; P.pk2[(size_t)((l + 1) & 1) * 131072 + n * 512 + u] = a; }
      else   { smP[u] = a; }
    }
    b_slice(P, b, lane, wave, l + 1, false);
    __syncthreads();
    {                                   // rare pipes layer l+1
      int cnt = smI[256]; if (cnt > 256) cnt = 256;
      const int np = (l + 1) & 1;
      for (int i = 0; i < cnt; ++i)
        bias_row_pipe(P.rareBias + (size_t)(n * 256 + i) * 128, smPD + i * 8 + np * 4,
                      P.bpW + (size_t)(l + 1) * 65536, P.bpB + (l + 1) * 512,
                      P.bowW + (size_t)(l + 1) * 65536, P.bowB + (l + 1) * 128,
                      smW, smB, t);
    }
  }
}

// ---------------------------------------------------------------------------
extern "C" void kernel_launch(void* const* d_in, const int* in_sizes, int n_in,
                              void* d_out, int out_size, void* d_ws, size_t ws_size,
                              hipStream_t stream) {
  char* p = (char*)d_ws;
  auto carve = [&](size_t bytes) -> void* {
    void* r = (void*)p;
    p += (bytes + 255) & ~(size_t)255;
    return r;
  };

  Params P;
  P.X     = (const float*)d_in[0];
  P.E     = (const float*)d_in[1];
  P.nbr   = (const float*)d_in[2];
  P.embW  = (const float*)d_in[3];
  P.embB  = (const float*)d_in[4];
  P.boutW = (const float*)d_in[5];
  P.boutB = (const float*)d_in[6];
  P.qpW   = (const float*)d_in[7];
  P.qpB   = (const float*)d_in[8];
  P.kpW   = (const float*)d_in[9];
  P.kpB   = (const float*)d_in[10];
  P.qoW   = (const float*)d_in[11];
  P.qoB   = (const float*)d_in[12];
  P.koW   = (const float*)d_in[13];
  P.koB   = (const float*)d_in[14];
  P.bpW   = (const float*)d_in[15];
  P.bpB   = (const float*)d_in[16];
  P.bowW  = (const float*)d_in[17];
  P.bowB  = (const float*)d_in[18];
  P.qlnG  = (const float*)d_in[19];
  P.qlnB  = (const float*)d_in[20];
  P.klnG  = (const float*)d_in[21];
  P.klnB  = (const float*)d_in[22];
  P.out   = (float*)d_out;

  P.pk2      = (float*)carve((size_t)2 * 256 * 512 * 4);
  P.bz       = (float*)carve(2 * 512 * 4);
  P.bg       = (float*)carve(2 * 512 * 4);
  P.rowz     = (float*)carve(2 * 128 * 4);
  P.rowg     = (float*)carve(2 * 128 * 4);
  P.partial  = (float*)carve(4 * 2 * 256 * 4);
  P.rareBias = (float*)carve((size_t)65536 * 128 * 4);

  void* args[] = { &P };
  hipLaunchCooperativeKernel((const void*)crakn, dim3(256), dim3(1024), args, 0, stream);
}

// Round 10
// 251.299 us; speedup vs baseline: 1.7062x; 1.7062x over previous
//
#include <hip/hip_runtime.h>
#include <hip/hip_cooperative_groups.h>

namespace cg = cooperative_groups;

struct Params {
  const float *X, *E, *nbr;
  const float *embW, *embB, *boutW, *boutB;
  const float *qpW, *qpB, *kpW, *kpB, *qoW, *qoB, *koW, *koB;
  const float *bpW, *bpB, *bowW, *bowB;
  const float *qlnG, *qlnB, *klnG, *klnB;
  float *out;
  float *pkT;      // [4][512][256] all-layer transposed keys (only cross-block data)
  float *rareRow;  // [65536][128] rare-pair bias rows (own-block use only)
};

__device__ __forceinline__ float mishf(float x) {
  float sp = (x > 20.f) ? x : log1pf(expf(x));
  return x * tanhf(sp);
}

// Full bias pipe for one rare-pair row, one layer (own-block; barriers inside)
__device__ void rare_pipe(float* row, float* drow,
                          const float* __restrict__ Wp, const float* __restrict__ Bp,
                          const float* __restrict__ Wo, const float* __restrict__ Bo,
                          float* smW, float* smS, int t) {
  const int lane = t & 63, wave = t >> 6;
  if (t < 128) smS[t] = row[t];
  __syncthreads();
  { const int o = t & 511, kh = t >> 9;
    const float* Wc = Wp + (kh * 64) * 512 + o;
    const float* rc = smS + kh * 64;
    float a = (kh == 0) ? Bp[o] : 0.f;
    #pragma unroll 8
    for (int c = 0; c < 64; ++c) a = fmaf(rc[c], Wc[c * 512], a);
    smW[t] = a; }
  __syncthreads();
  if (t < 512) smS[128 + t] = smW[t] + smW[512 + t];
  __syncthreads();
  if (wave < 4) {
    float e1 = smS[128 + wave * 128 + lane], e2 = smS[128 + wave * 128 + 64 + lane];
    float s = e1 * e1 + e2 * e2;
    #pragma unroll
    for (int sh = 32; sh; sh >>= 1) s += __shfl_xor(s, sh);
    if (lane == 0) drow[wave] = sqrtf(s);
  }
  { const int c = t & 127, ch = t >> 7;
    const float* Woc = Wo + (ch * 64) * 128 + c;
    const float* bc = smS + 128 + ch * 64;
    float a = 0.f;
    #pragma unroll 8
    for (int o2 = 0; o2 < 64; ++o2) a = fmaf(bc[o2], Woc[o2 * 128], a);
    smW[t] = a; }
  __syncthreads();
  if (t < 128) {
    float a = Bo[t];
    #pragma unroll
    for (int j = 0; j < 8; ++j) a += smW[t + 128 * j];
    row[t] = mishf(a);
  }
  __syncthreads();
}

// 256 blocks x 1024 threads; ONE grid.sync; all per-n state in LDS.
__global__ void __launch_bounds__(1024, 4) crakn(Params P) {
  cg::grid_group grid = cg::this_grid();
  const int b = blockIdx.x, t = threadIdx.x;
  const int lane = t & 63, wave = t >> 6;
  const int n = b;

  // persistent across the whole kernel
  __shared__ float smPQ[2048];          // pq for all 4 layers
  __shared__ float smKr[512];           // current pk row
  __shared__ float smQ[64], smKq[64];
  __shared__ float smNbr[256];
  __shared__ int   smMap[256];          // -2 zero-class, -1 gen-class, >=0 rare idx
  __shared__ float smPD[4096];          // rare diffs [pair][layer][head]
  __shared__ float smDiff[32];          // [layer][class][head]
  __shared__ float smRow[256], smRowN[256];  // zero/gen bias rows (cur/next)
  __shared__ float smPred[1];
  __shared__ int   smI[257];
  __shared__ float smD[256];
  // scratch
  __shared__ float smW[1024];
  __shared__ float smB2[1024];
  __shared__ float smH[64];

  // ================= Phase A: embed / pred0 / distances =================
  {
    if (t < 256) smB2[t] = P.X[n * 256 + t];
    if (t < 256) smNbr[t] = P.nbr[t];
    if (t == 0) smI[256] = 0;
    __syncthreads();
    { const int d = t & 63, ch = t >> 6;
      const float* W = P.embW + (ch * 16) * 64 + d;
      const float* xr = smB2 + ch * 16;
      float acc = 0.f;
      #pragma unroll
      for (int f = 0; f < 16; ++f) acc = fmaf(xr[f], W[f * 64], acc);
      smW[t] = acc; }
    float pp = (t < 256) ? smB2[t] * P.boutW[t] : 0.f;
    #pragma unroll
    for (int s = 32; s; s >>= 1) pp += __shfl_xor(pp, s);
    if (t < 256 && lane == 0) smH[wave] = pp;
    __syncthreads();
    if (t < 64) {
      float nd = P.embB[t];
      #pragma unroll
      for (int j = 0; j < 16; ++j) nd += smW[t + 64 * j];
      smQ[t] = nd; smKq[t] = nd;
    }
    if (t == 0) smPred[0] = smH[0] + smH[1] + smH[2] + smH[3] + P.boutB[0];
    __syncthreads();
    if (t < 25) ((float4*)(smB2 + 384))[t] = ((const float4*)(P.E + n * 100))[t];
    __syncthreads();
    if (t < 256) {                      // distances, thread = m
      const int m = t;
      const float4* em = (const float4*)(P.E + m * 100);
      const float4* en = (const float4*)(smB2 + 384);
      float sq = 0.f;
      #pragma unroll 5
      for (int jj = 0; jj < 25; ++jj) {
        float4 a = en[jj], c = em[jj];
        float dx = a.x - c.x, dy = a.y - c.y, dz = a.z - c.z, dw = a.w - c.w;
        sq += dx * dx + dy * dy + dz * dz + dw * dw;
      }
      float dd = (sq > 0.f) ? sqrtf(sq) : 0.f;
      // exp(-127*(d-c)^2), c in [0,1]: fp32-underflows to exactly 0 for d>=1.905.
      // d==0 rows identical -> shared zero-class; underflowed -> shared gen-class.
      int mv;
      if (dd == 0.f) mv = -2;
      else if (dd < 1.905f) {
        int i = atomicAdd(&smI[256], 1);
        smI[i] = m; smD[i] = dd;
        mv = i;
      } else mv = -1;
      smMap[m] = mv;
    }
    if (t < 128) {                      // init shared bias rows (both classes)
      float c = (float)t * (1.f / 127.f);
      smRow[t] = expf(-127.f * c * c);  // zero class (d == 0)
      smRow[128 + t] = 0.f;             // gen class (underflowed)
    }
    __syncthreads();
    { int cnt = smI[256]; if (cnt > 256) cnt = 256;   // rare RBF rows (none in data)
      for (int i = 0; i < cnt; ++i) if (t < 128) {
        float dd = smD[i] - (float)t * (1.f / 127.f);
        P.rareRow[(size_t)(n * 256 + i) * 128 + t] = expf(-127.f * dd * dd);
      } }
    __syncthreads();
  }

  // ============ Phase 1: full q/k chain + bias chains, NO grid syncs ============
  for (int l = 0; l < 4; ++l) {
    // proj(l): pq -> LDS, pk -> smKr + transposed global pkT[l]
    { const int g = t >> 9, u = t & 511;
      const float* Wp = (g ? P.kpW : P.qpW) + (size_t)l * 32768;
      const float* Bp = (g ? P.kpB : P.qpB) + l * 512;
      const float* xs = g ? smKq : smQ;
      float a = Bp[u];
      #pragma unroll 8
      for (int d = 0; d < 64; ++d) a = fmaf(xs[d], Wp[d * 512 + u], a);
      if (g) { smKr[u] = a; P.pkT[(size_t)l * 131072 + u * 256 + n] = a; }
      else smPQ[l * 512 + u] = a; }
    // bias GEMM1: b_l = row_l @ bpW[l] + bpB[l], both classes (redundant per block)
    { const int cls = t >> 9, o = t & 511;
      const float* Wp = P.bpW + (size_t)l * 65536;
      const float* rc = smRow + cls * 128;
      float a = P.bpB[l * 512 + o];
      #pragma unroll 8
      for (int c = 0; c < 128; ++c) a = fmaf(rc[c], Wp[c * 512 + o], a);
      smB2[cls * 512 + o] = a; }
    __syncthreads();
    if (wave < 8) {                     // per-head norms -> smDiff
      const int cls = wave >> 2, h = wave & 3;
      float e1 = smB2[cls * 512 + h * 128 + lane], e2 = smB2[cls * 512 + h * 128 + 64 + lane];
      float s = e1 * e1 + e2 * e2;
      #pragma unroll
      for (int sh = 32; sh; sh >>= 1) s += __shfl_xor(s, sh);
      if (lane == 0) smDiff[(l * 2 + cls) * 4 + h] = sqrtf(s);
    }
    // bias GEMM2 split-K: row_{l+1} = mish(b_l @ bowW[l] + bowB[l])
    { const int cls = t >> 9, ch = (t >> 7) & 3, i = t & 127;
      const float* Wo = P.bowW + (size_t)l * 65536;
      const float* bc = smB2 + cls * 512 + ch * 128;
      float a = 0.f;
      #pragma unroll 8
      for (int o2 = 0; o2 < 128; ++o2) a = fmaf(bc[o2], Wo[(ch * 128 + o2) * 128 + i], a);
      smW[t] = a; }
    __syncthreads();
    if (t < 256) {
      const int cls = t >> 7, i = t & 127;
      float a = P.bowB[l * 128 + i] + smW[cls * 512 + i] + smW[cls * 512 + 128 + i]
              + smW[cls * 512 + 256 + i] + smW[cls * 512 + 384 + i];
      smRowN[t] = mishf(a);
    }
    __syncthreads();
    if (t < 256) smRow[t] = smRowN[t];
    // Bupd(l): q,k <- LN(x + mish(perm(p)@W + B)) (own-block; only needed l<3)
    if (l < 3) {
      const int g = t >> 9, u = t & 511;
      const float* prow = g ? smKr : (smPQ + l * 512);
      const float* W = (g ? P.koW : P.qoW) + (size_t)l * 32768;
      { const int d = u & 63, ch = u >> 6;
        float acc = 0.f;
        #pragma unroll 8
        for (int rr = 0; rr < 64; ++rr) {
          int r = ch * 64 + rr;
          acc = fmaf(prow[((r & 3) << 7) | (r >> 2)], W[r * 64 + d], acc);
        }
        smW[t] = acc; }
      __syncthreads();
      if (u < 64) {
        float* x = g ? smKq : smQ;
        const float* B = (g ? P.koB : P.qoB) + l * 64;
        float acc = B[u];
        #pragma unroll
        for (int j = 0; j < 8; ++j) acc += smW[g * 512 + u + 64 * j];
        float xv = x[u] + mishf(acc);
        float mean = xv;
        #pragma unroll
        for (int s = 32; s; s >>= 1) mean += __shfl_xor(mean, s);
        mean *= (1.f / 64.f);
        float dv = xv - mean, var = dv * dv;
        #pragma unroll
        for (int s = 32; s; s >>= 1) var += __shfl_xor(var, s);
        var *= (1.f / 64.f);
        const float* G  = (g ? P.klnG : P.qlnG) + l * 64;
        const float* Bb = (g ? P.klnB : P.qlnB) + l * 64;
        x[u] = dv * rsqrtf(var + 1e-5f) * G[u] + Bb[u];
      }
    }
    __syncthreads();
    // rare-pair pipes for layer l (own-block; none in this data)
    { int cnt = smI[256]; if (cnt > 256) cnt = 256;
      for (int i = 0; i < cnt; ++i)
        rare_pipe(P.rareRow + (size_t)(n * 256 + i) * 128, smPD + i * 16 + l * 4,
                  P.bpW + (size_t)l * 65536, P.bpB + l * 512,
                  P.bowW + (size_t)l * 65536, P.bowB + l * 128, smW, smB2, t); }
  }

  grid.sync();   // the ONLY grid-wide sync: pkT (all layers) now visible

  // ============ Phase 2: attention C(0..3), all from LDS + pkT ============
  for (int l = 0; l < 4; ++l) {
    const int h = t >> 8, m = t & 255;
    const int cls = smMap[m];
    const float bd = (cls == -2) ? smDiff[(l * 2 + 0) * 4 + h]
                   : (cls == -1) ? smDiff[(l * 2 + 1) * 4 + h]
                   : smPD[cls * 16 + l * 4 + h];
    const float val = (m == n) ? smPred[0] : smNbr[m];
    const float* pt = P.pkT + (size_t)l * 131072 + (size_t)(h * 128) * 256 + m;
    const float* qv = smPQ + l * 512 + h * 128;
    float dot = 0.f;
    #pragma unroll 8
    for (int j = 0; j < 128; ++j) dot = fmaf(qv[j], pt[j * 256], dot);
    float lg = dot * 0.08838834764831845f + bd;   // 1/sqrt(128)
    float wm = lg;
    #pragma unroll
    for (int s = 32; s; s >>= 1) wm = fmaxf(wm, __shfl_xor(wm, s));
    if (lane == 0) smH[wave] = wm;
    __syncthreads();
    float mx = fmaxf(fmaxf(smH[h * 4], smH[h * 4 + 1]),
                     fmaxf(smH[h * 4 + 2], smH[h * 4 + 3]));
    float e = expf(lg - mx);
    float s1 = e, s2 = e * val;
    #pragma unroll
    for (int s = 32; s; s >>= 1) { s1 += __shfl_xor(s1, s); s2 += __shfl_xor(s2, s); }
    if (lane == 0) { smH[16 + wave] = s1; smH[32 + wave] = s2; }
    __syncthreads();
    if (t == 0) {
      float p = 0.f;
      #pragma unroll
      for (int hh = 0; hh < 4; ++hh) {
        float den = smH[16 + hh * 4] + smH[17 + hh * 4] + smH[18 + hh * 4] + smH[19 + hh * 4];
        float ws  = smH[32 + hh * 4] + smH[33 + hh * 4] + smH[34 + hh * 4] + smH[35 + hh * 4];
        p += 0.25f * (ws / den);
      }
      smPred[0] = p;                    // only ever read by this block
      if (l == 3) P.out[n] = p;
    }
    __syncthreads();
  }
}

// ---------------------------------------------------------------------------
extern "C" void kernel_launch(void* const* d_in, const int* in_sizes, int n_in,
                              void* d_out, int out_size, void* d_ws, size_t ws_size,
                              hipStream_t stream) {
  char* p = (char*)d_ws;
  auto carve = [&](size_t bytes) -> void* {
    void* r = (void*)p;
    p += (bytes + 255) & ~(size_t)255;
    return r;
  };

  Params P;
  P.X     = (const float*)d_in[0];
  P.E     = (const float*)d_in[1];
  P.nbr   = (const float*)d_in[2];
  P.embW  = (const float*)d_in[3];
  P.embB  = (const float*)d_in[4];
  P.boutW = (const float*)d_in[5];
  P.boutB = (const float*)d_in[6];
  P.qpW   = (const float*)d_in[7];
  P.qpB   = (const float*)d_in[8];
  P.kpW   = (const float*)d_in[9];
  P.kpB   = (const float*)d_in[10];
  P.qoW   = (const float*)d_in[11];
  P.qoB   = (const float*)d_in[12];
  P.koW   = (const float*)d_in[13];
  P.koB   = (const float*)d_in[14];
  P.bpW   = (const float*)d_in[15];
  P.bpB   = (const float*)d_in[16];
  P.bowW  = (const float*)d_in[17];
  P.bowB  = (const float*)d_in[18];
  P.qlnG  = (const float*)d_in[19];
  P.qlnB  = (const float*)d_in[20];
  P.klnG  = (const float*)d_in[21];
  P.klnB  = (const float*)d_in[22];
  P.out   = (float*)d_out;

  P.pkT     = (float*)carve((size_t)4 * 512 * 256 * 4);
  P.rareRow = (float*)carve((size_t)65536 * 128 * 4);

  void* args[] = { &P };
  hipLaunchCooperativeKernel((const void*)crakn, dim3(256), dim3(1024), args, 0, stream);
}